// Round 5
// baseline (508.513 us; speedup 1.0000x reference)
//
#include <hip/hip_runtime.h>
#include <hip/hip_fp16.h>
#include <cstdint>
#include <cstdio>

#define N_NODES 10000
#define BATCH   32
#define UNITS   64
#define F_DIM   66            // 2 + 64
#define XROW    2048          // fp8 state-part row bytes (64 f * 32 b)
#define KPAD    96            // MFMA K padded (3 x 32)
#define ASTR    104           // accH row stride in halves (96 + 8 pad)
#define GRP     8             // gather group size (2 groups in flight = 16 loads/wave)

typedef float v2f __attribute__((ext_vector_type(2)));
typedef float f32x4 __attribute__((ext_vector_type(4)));
typedef _Float16 half8 __attribute__((ext_vector_type(8)));

__device__ __forceinline__ float sigmoidf(float x) {
  return 1.0f / (1.0f + __expf(-x));
}

// ---------------- CSR build (+ weight prep folded in) ----------------
__global__ __launch_bounds__(256) void hist_k(const int* __restrict__ rows,
                                              int* __restrict__ counts, int E2,
                                              const float* __restrict__ w1,
                                              const float* __restrict__ w2,
                                              _Float16* __restrict__ w1T,
                                              _Float16* __restrict__ w2T) {
  int e = blockIdx.x * 256 + threadIdx.x;
  if (e < E2) atomicAdd(&counts[rows[e]], 1);
  if (e < 128 * KPAD) {
    int j = e / KPAD, f = e % KPAD;
    w1T[e] = (f < 66) ? (_Float16)w1[f * 128 + j] : (_Float16)0.0f;
  } else if (e < 128 * KPAD + 64 * KPAD) {
    int k = e - 128 * KPAD;
    int j = k / KPAD, f = k % KPAD;
    w2T[k] = (f < 66) ? (_Float16)w2[f * 64 + j] : (_Float16)0.0f;
  }
}

// Single block; counts staged through LDS with coalesced int4 loads.
__global__ __launch_bounds__(256) void scan_k(const int* __restrict__ counts,
                                              int* __restrict__ rowptr,
                                              int* __restrict__ wofs, int n) {
  __shared__ int lbuf[10240];
  __shared__ int sums[256];
  int t = threadIdx.x;
  for (int i = t; i < N_NODES / 4; i += 256)
    reinterpret_cast<int4*>(lbuf)[i] = reinterpret_cast<const int4*>(counts)[i];
  for (int i = N_NODES + t; i < 10240; i += 256) lbuf[i] = 0;
  __syncthreads();
  int base = t * 40;
  int v[40];
  int run = 0;
#pragma unroll
  for (int i = 0; i < 40; ++i) { v[i] = run; run += lbuf[base + i]; }
  sums[t] = run;
  __syncthreads();
  for (int off = 1; off < 256; off <<= 1) {
    int x = (t >= off) ? sums[t - off] : 0;
    __syncthreads();
    sums[t] += x;
    __syncthreads();
  }
  int tbase = (t == 0) ? 0 : sums[t - 1];
#pragma unroll
  for (int i = 0; i < 40; ++i) lbuf[base + i] = tbase + v[i];
  __syncthreads();
  for (int i = t; i < N_NODES / 4; i += 256) {
    int4 w = reinterpret_cast<int4*>(lbuf)[i];
    reinterpret_cast<int4*>(rowptr)[i] = w;
    reinterpret_cast<int4*>(wofs)[i] = w;
  }
  if (t == 255) rowptr[N_NODES] = sums[255];
}

// ---------------- fused scatter + phase-1 feature build ----------------
__device__ __forceinline__ void pack_row_fp8(const float* T, int n, int t,
                                             unsigned char* xcat8) {
  int k0 = t * 8;
  int f8 = k0 >> 5;
  int b0 = k0 & 31;
  const float* Ts = &T[(f8 + 2) * 33 + b0];
  int d0 = __builtin_amdgcn_cvt_pk_fp8_f32(Ts[0], Ts[1], 0, false);
  d0     = __builtin_amdgcn_cvt_pk_fp8_f32(Ts[2], Ts[3], d0, true);
  int d1 = __builtin_amdgcn_cvt_pk_fp8_f32(Ts[4], Ts[5], 0, false);
  d1     = __builtin_amdgcn_cvt_pk_fp8_f32(Ts[6], Ts[7], d1, true);
  *reinterpret_cast<uint2*>(xcat8 + (size_t)n * XROW + k0) = make_uint2(d0, d1);
}

// blocks [0, N_NODES): build xcat8 + xin for node n = blockIdx.x
// blocks [N_NODES, ...): scatter edges into ecv = {col*2048, bitcast(val)}
__global__ __launch_bounds__(256) void scat_build(const int* __restrict__ rows,
                                                  const int* __restrict__ cols,
                                                  const float* __restrict__ vals,
                                                  int* __restrict__ wofs,
                                                  int2* __restrict__ ecv, int E2,
                                                  const float* __restrict__ inputs,
                                                  const float* __restrict__ state,
                                                  unsigned char* __restrict__ xcat8,
                                                  __half2* __restrict__ xin) {
  int blk = blockIdx.x, t = threadIdx.x;
  if (blk >= N_NODES) {
    int e = (blk - N_NODES) * 256 + t;
    if (e < E2) {
      int r = rows[e];
      int p = atomicAdd(&wofs[r], 1);
      ecv[p] = make_int2(cols[e] << 11, __float_as_int(vals[e]));
    }
    return;
  }
  int n = blk;
  __shared__ float T[66 * 33];
  int f = t & 63, bq = t >> 6;
#pragma unroll
  for (int bb = 0; bb < 8; ++bb) {
    int b = bq + bb * 4;
    T[(f + 2) * 33 + b] = state[(size_t)b * 640000 + (size_t)n * 64 + f];
  }
  if (t < 64) {
    int b0 = t & 31, f0 = t >> 5;
    T[f0 * 33 + b0] = inputs[(size_t)b0 * 20000 + (size_t)n * 2 + f0];
  }
  __syncthreads();
  pack_row_fp8(T, n, t, xcat8);
  if (t < 32) {
    int f0 = t >> 4, b = (t & 15) * 2;
    xin[(size_t)n * 32 + t] = __floats2half2_rn(T[f0 * 33 + b], T[f0 * 33 + b + 1]);
  }
}

// ---------------- yin = M @ X_in ----------------
// Node-per-wave, 4 edges in parallel (16 lanes x 8B each), shfl reduce.
__global__ __launch_bounds__(256) void yin_k(const int* __restrict__ rowptr,
                                             const int2* __restrict__ ecv,
                                             const __half* __restrict__ xin,
                                             float* __restrict__ yin) {
  int n = (blockIdx.x * 256 + threadIdx.x) >> 6;     // node per wave
  if (n >= N_NODES) return;
  int lane  = threadIdx.x & 63;
  int eslot = lane >> 4;         // 0..3 : which edge of the 4-group
  int sub   = lane & 15;         // 0..15: which 8B chunk of the 128B row
  unsigned sb = (unsigned)sub * 8u;

  float acc0 = 0.0f, acc1 = 0.0f, acc2 = 0.0f, acc3 = 0.0f;
  int s = rowptr[n], e = rowptr[n + 1];
  const char* xb = reinterpret_cast<const char*>(xin);
  for (int ee = s + eslot; ee < e; ee += 4) {
    int2 cv = ecv[ee];
    float v = __int_as_float(cv.y);
    unsigned off = ((unsigned)cv.x >> 4) + sb;       // col*128 + sub*8
    uint2 raw = *reinterpret_cast<const uint2*>(xb + off);
    __half2 h0 = *reinterpret_cast<__half2*>(&raw.x);
    __half2 h1 = *reinterpret_cast<__half2*>(&raw.y);
    float2 x0 = __half22float2(h0);
    float2 x1 = __half22float2(h1);
    acc0 += v * x0.x; acc1 += v * x0.y;
    acc2 += v * x1.x; acc3 += v * x1.y;
  }
  // reduce across the 4 edge slots (lane ^16, ^32)
#pragma unroll
  for (int m = 16; m <= 32; m <<= 1) {
    acc0 += __shfl_xor(acc0, m);
    acc1 += __shfl_xor(acc1, m);
    acc2 += __shfl_xor(acc2, m);
    acc3 += __shfl_xor(acc3, m);
  }
  if (eslot == 0) {
    *reinterpret_cast<float4*>(yin + (size_t)n * 64 + sub * 4) =
        make_float4(acc0, acc1, acc2, acc3);
  }
}

// Consume one 8B chunk (8 fp8) into 4 packed-f32 accumulators (v_pk_fma_f32).
__device__ __forceinline__ void consume8f8(uint2 u, float v, v2f* acc) {
  v2f p0 = __builtin_amdgcn_cvt_pk_f32_fp8((int)u.x, false);
  v2f p1 = __builtin_amdgcn_cvt_pk_f32_fp8((int)u.x, true);
  v2f p2 = __builtin_amdgcn_cvt_pk_f32_fp8((int)u.y, false);
  v2f p3 = __builtin_amdgcn_cvt_pk_f32_fp8((int)u.y, true);
  v2f vv = {v, v};
  acc[0] += vv * p0;
  acc[1] += vv * p1;
  acc[2] += vv * p2;
  acc[3] += vv * p3;
}

// Load one group of GRP edges: edge meta via UNIFORM (scalar) loads, gathers
// issued as SADDR-form loads (uniform base + per-thread offset).
__device__ __forceinline__ void ld_grp(const int2* __restrict__ ep, int gsz,
                                       const unsigned char* __restrict__ xcat8,
                                       unsigned t8, uint2* r, float* v) {
#pragma unroll
  for (int q = 0; q < GRP; ++q) {
    int2 c = ep[q];                       // uniform -> s_load
    if (q >= gsz) { c.x = 0; c.y = 0; }   // masked tail: row 0, weight 0 (scalar ops)
    unsigned off = (unsigned)c.x + t8;    // 1 VALU add (SGPR + VGPR)
    r[q] = *reinterpret_cast<const uint2*>(xcat8 + off);
    v[q] = __int_as_float(c.y);           // stays scalar
  }
}

__device__ __forceinline__ void cons_grp(const uint2* r, const float* v, v2f* acc) {
#pragma unroll
  for (int q = 0; q < GRP; ++q) consume8f8(r[q], v[q], acc);
}

// Shared SpMM body: scalar edge stream, groups of GRP, double-buffered
// (2*GRP loads in flight / wave), no LDS edge staging, no barriers.
// Result staged to fp16 accH[b][k]: k=0,1 from yin, k=2..65 state part,
// k=66..95 zero-padded for MFMA.
__device__ __forceinline__ void spmm_body(int n, int t,
                                          const int* __restrict__ rowptr,
                                          const int2* __restrict__ ecv,
                                          const unsigned char* __restrict__ xcat8,
                                          const float* __restrict__ yin,
                                          _Float16* accH) {
  v2f acc[4];
#pragma unroll
  for (int i = 0; i < 4; ++i) acc[i] = (v2f){0.0f, 0.0f};

  unsigned t8 = (unsigned)t * 8u;
  int s = rowptr[n], e = rowptr[n + 1];
  int ne = e - s;
  int ng = (ne + GRP - 1) / GRP;
  const int2* ep = ecv + s;

  uint2 rA[GRP], rB[GRP];
  float vA[GRP], vB[GRP];
  ld_grp(ep, ne, xcat8, t8, rA, vA);
  int g = 1;
  for (; g + 1 < ng; g += 2) {
    ld_grp(ep + GRP * g, ne - GRP * g, xcat8, t8, rB, vB);
    cons_grp(rA, vA, acc);
    ld_grp(ep + GRP * (g + 1), ne - GRP * (g + 1), xcat8, t8, rA, vA);
    cons_grp(rB, vB, acc);
  }
  if (g < ng) {
    ld_grp(ep + GRP * g, ne - GRP * g, xcat8, t8, rB, vB);
    cons_grp(rA, vA, acc);
    cons_grp(rB, vB, acc);
  } else {
    cons_grp(rA, vA, acc);
  }

  // ---- stage into fp16 accH[b][k] ----
  {
    int f8 = t >> 2;
    int b0 = (t & 3) * 8;
    float a[8] = {acc[0].x, acc[0].y, acc[1].x, acc[1].y,
                  acc[2].x, acc[2].y, acc[3].x, acc[3].y};
    _Float16* dst = accH + (f8 + 2);
#pragma unroll
    for (int i = 0; i < 8; ++i) {
      dst[(b0 + i) * ASTR] = (_Float16)a[i];
    }
  }
  if (t < 64) {
    int f = t >> 5, b = t & 31;
    accH[b * ASTR + f] = (_Float16)yin[(size_t)n * 64 + t];
  }
  for (int id = t; id < 32 * 19; id += 256) {
    int b = id / 19, c = id % 19;
    *reinterpret_cast<unsigned int*>(
        reinterpret_cast<char*>(accH) + b * (ASTR * 2) + 132 + c * 4) = 0u;
  }
  __syncthreads();
}

// ---------------- phase 1: SpMM + MFMA GEMM + sigmoid ----------------
// LDS: single 8704B region; accH (6656B) aliased by vstage after fragment loads.
// n < 5000 : outputs are r-gates of nodes 2n,2n+1 -> emit fp8 x2 rows (r*state).
// n >= 5000: outputs are u-gates -> write fp16 valu rows (node index n-5000).
__global__ __launch_bounds__(256, 8) void gcn1(const int* __restrict__ rowptr,
                                               const int2* __restrict__ ecv,
                                               const unsigned char* __restrict__ xcat8,
                                               const float* __restrict__ yin,
                                               const _Float16* __restrict__ w1T,
                                               const float* __restrict__ b1,
                                               const float* __restrict__ state,
                                               unsigned char* __restrict__ xcat2,
                                               __half* __restrict__ valu) {
  int n = blockIdx.x, t = threadIdx.x;
  __shared__ __align__(16) char smem[32 * 136 * 2];   // 8704 B shared region
  _Float16* accH = reinterpret_cast<_Float16*>(smem); // 6656 B during SpMM

  spmm_body(n, t, rowptr, ecv, xcat8, yin, accH);

  int wv = t >> 6, l = t & 63;
  int mt = wv & 1, ntb = (wv >> 1) * 4;
  int lr = l & 15, lg = l >> 4;
  const _Float16* aB = accH + (size_t)(mt * 16 + lr) * ASTR + lg * 8;
  half8 afr0 = *reinterpret_cast<const half8*>(aB);
  half8 afr1 = *reinterpret_cast<const half8*>(aB + 32);
  half8 afr2 = *reinterpret_cast<const half8*>(aB + 64);
  __syncthreads();                                    // accH dead; alias as vstage
  _Float16* vstage = reinterpret_cast<_Float16*>(smem);

#pragma unroll
  for (int tt = 0; tt < 4; ++tt) {
    int j = (ntb + tt) * 16 + lr;
    const _Float16* wB = w1T + (size_t)j * KPAD + lg * 8;
    f32x4 c = {0.0f, 0.0f, 0.0f, 0.0f};
    c = __builtin_amdgcn_mfma_f32_16x16x32_f16(afr0, *reinterpret_cast<const half8*>(wB), c, 0, 0, 0);
    c = __builtin_amdgcn_mfma_f32_16x16x32_f16(afr1, *reinterpret_cast<const half8*>(wB + 32), c, 0, 0, 0);
    c = __builtin_amdgcn_mfma_f32_16x16x32_f16(afr2, *reinterpret_cast<const half8*>(wB + 64), c, 0, 0, 0);
    float bj = b1[j];
#pragma unroll
    for (int i = 0; i < 4; ++i) {
      int b = mt * 16 + lg * 4 + i;
      vstage[b * 136 + j] = (_Float16)sigmoidf(c[i] + bj);
    }
  }
  __syncthreads();

  if (n < 5000) {
    // r-path: f = t&63 so state reads are 256B/wave coalesced.
    int nn_i = t >> 7;
    int f    = t & 63;
    int bg   = (t >> 6) & 1;
    int nn = n * 2 + nn_i;
    int jj = nn_i * 64 + f;
    const float* sp = state + (size_t)nn * 64 + f;
    const _Float16* vp = vstage + jj;
    int bbase = bg * 16;
    unsigned int d[4];
#pragma unroll
    for (int q = 0; q < 4; ++q) {
      int b0 = bbase + q * 4;
      float x0 = (float)vp[(b0 + 0) * 136] * sp[(size_t)(b0 + 0) * 640000];
      float x1 = (float)vp[(b0 + 1) * 136] * sp[(size_t)(b0 + 1) * 640000];
      float x2 = (float)vp[(b0 + 2) * 136] * sp[(size_t)(b0 + 2) * 640000];
      float x3 = (float)vp[(b0 + 3) * 136] * sp[(size_t)(b0 + 3) * 640000];
      int dd = __builtin_amdgcn_cvt_pk_fp8_f32(x0, x1, 0, false);
      dd     = __builtin_amdgcn_cvt_pk_fp8_f32(x2, x3, dd, true);
      d[q] = (unsigned)dd;
    }
    *reinterpret_cast<uint4*>(xcat2 + (size_t)nn * XROW + f * 32 + bbase) =
        make_uint4(d[0], d[1], d[2], d[3]);
  } else {
    // u-path: vectorized copy to valu (node index n-5000)
    int b = t >> 3, jg = t & 7;
    const uint4* src = reinterpret_cast<const uint4*>(vstage + b * 136 + jg * 16);
    uint4 q0 = src[0];
    uint4 q1 = src[1];
    __half* vb = valu + (size_t)(n - 5000) * 4096 + b * 128 + jg * 16;
    *reinterpret_cast<uint4*>(vb) = q0;
    *reinterpret_cast<uint4*>(vb + 8) = q1;
  }
}

// ---------------- phase 2: SpMM + MFMA GEMM(96->64) + relu + gate -> out ----------------
__global__ __launch_bounds__(256, 8) void gcn2(const int* __restrict__ rowptr,
                                               const int2* __restrict__ ecv,
                                               const unsigned char* __restrict__ xcat2,
                                               const float* __restrict__ yin,
                                               const _Float16* __restrict__ w2T,
                                               const float* __restrict__ b2,
                                               const __half* __restrict__ valu,
                                               const float* __restrict__ state,
                                               float* __restrict__ out) {
  int n = blockIdx.x, t = threadIdx.x;
  __shared__ __align__(16) char smem[32 * 68 * 4];    // 8704 B shared region
  _Float16* accH = reinterpret_cast<_Float16*>(smem); // 6656 B during SpMM

  spmm_body(n, t, rowptr, ecv, xcat2, yin, accH);

  int wv = t >> 6, l = t & 63;
  int mt = wv & 1, ntb = (wv >> 1) * 2;
  int lr = l & 15, lg = l >> 4;
  const _Float16* aB = accH + (size_t)(mt * 16 + lr) * ASTR + lg * 8;
  half8 afr0 = *reinterpret_cast<const half8*>(aB);
  half8 afr1 = *reinterpret_cast<const half8*>(aB + 32);
  half8 afr2 = *reinterpret_cast<const half8*>(aB + 64);
  __syncthreads();                                    // accH dead; alias as ostage
  float* ostage = reinterpret_cast<float*>(smem);     // [32][68]

#pragma unroll
  for (int tt = 0; tt < 2; ++tt) {
    int j = (ntb + tt) * 16 + lr;
    const _Float16* wB = w2T + (size_t)j * KPAD + lg * 8;
    f32x4 c = {0.0f, 0.0f, 0.0f, 0.0f};
    c = __builtin_amdgcn_mfma_f32_16x16x32_f16(afr0, *reinterpret_cast<const half8*>(wB), c, 0, 0, 0);
    c = __builtin_amdgcn_mfma_f32_16x16x32_f16(afr1, *reinterpret_cast<const half8*>(wB + 32), c, 0, 0, 0);
    c = __builtin_amdgcn_mfma_f32_16x16x32_f16(afr2, *reinterpret_cast<const half8*>(wB + 64), c, 0, 0, 0);
    float bj = b2[j];
#pragma unroll
    for (int i = 0; i < 4; ++i) {
      int b = mt * 16 + lg * 4 + i;
      ostage[b * 68 + j] = fmaxf(c[i] + bj, 0.0f);
    }
  }
  __syncthreads();

  int bg = t >> 4, jg = t & 15;
  int n2 = n >> 1, no = n & 1;
  const __half* up = valu + (size_t)n2 * 4096 + (size_t)no * 64 + jg * 4;
#pragma unroll
  for (int i = 0; i < 2; ++i) {
    int b = bg * 2 + i;
    size_t idx = (size_t)b * 640000 + (size_t)n * 64 + jg * 4;
    float4 sv = *reinterpret_cast<const float4*>(state + idx);
    float4 cc = *reinterpret_cast<const float4*>(ostage + b * 68 + jg * 4);
    union { uint2 u; __half2 h[2]; } pk;
    pk.u = *reinterpret_cast<const uint2*>(up + (size_t)b * 128);
    float2 u01 = __half22float2(pk.h[0]);
    float2 u23 = __half22float2(pk.h[1]);
    float4 h;
    h.x = u01.x * sv.x + (1.0f - u01.x) * cc.x;
    h.y = u01.y * sv.y + (1.0f - u01.y) * cc.y;
    h.z = u23.x * sv.z + (1.0f - u23.x) * cc.z;
    h.w = u23.y * sv.w + (1.0f - u23.y) * cc.w;
    *reinterpret_cast<float4*>(out + idx) = h;
  }
}

// ---------------- host ----------------
static inline size_t alignup(size_t x) { return (x + 255) & ~(size_t)255; }

extern "C" void kernel_launch(void* const* d_in, const int* in_sizes, int n_in,
                              void* d_out, int out_size, void* d_ws, size_t ws_size,
                              hipStream_t stream) {
  const float* inputs = (const float*)d_in[0];
  const float* state  = (const float*)d_in[1];
  const int*   m_rows = (const int*)d_in[2];
  const int*   m_cols = (const int*)d_in[3];
  const float* m_vals = (const float*)d_in[4];
  const float* w1     = (const float*)d_in[5];
  const float* b1     = (const float*)d_in[6];
  const float* w2     = (const float*)d_in[7];
  const float* b2     = (const float*)d_in[8];
  float* out = (float*)d_out;

  const int N  = N_NODES;
  const int E2 = in_sizes[2];

  char* ws = (char*)d_ws;
  size_t off = 0;
  int* counts = (int*)(ws + off); off = alignup(off + (size_t)N * 4);
  int* rowptr = (int*)(ws + off); off = alignup(off + (size_t)(N + 1) * 4);
  int* wofs   = (int*)(ws + off); off = alignup(off + (size_t)N * 4);
  int2* ecv   = (int2*)(ws + off); off = alignup(off + (size_t)E2 * 8 + 256); // +slack for group over-read
  unsigned char* xcat8 = (unsigned char*)(ws + off); off = alignup(off + (size_t)N * XROW);
  unsigned char* xcat2 = (unsigned char*)(ws + off); off = alignup(off + (size_t)N * XROW);
  __half* valu = (__half*)(ws + off); off = alignup(off + (size_t)5000 * 4096 * 2);
  float* yin  = (float*)(ws + off); off = alignup(off + (size_t)N * 64 * 4);
  __half* xin = (__half*)(ws + off); off = alignup(off + (size_t)N * 64 * 2);
  _Float16* w1T = (_Float16*)(ws + off); off = alignup(off + (size_t)128 * KPAD * 2);
  _Float16* w2T = (_Float16*)(ws + off); off = alignup(off + (size_t)64 * KPAD * 2);
  if (off > ws_size) { return; }

  hipMemsetAsync(counts, 0, (size_t)N * 4, stream);

  int eb = (E2 + 255) / 256;
  hipLaunchKernelGGL(hist_k,     dim3(eb), dim3(256), 0, stream, m_rows, counts, E2,
                     w1, w2, w1T, w2T);
  hipLaunchKernelGGL(scan_k,     dim3(1),  dim3(256), 0, stream, counts, rowptr, wofs, N);
  hipLaunchKernelGGL(scat_build, dim3(N + eb), dim3(256), 0, stream,
                     m_rows, m_cols, m_vals, wofs, ecv, E2,
                     inputs, state, xcat8, (__half2*)xin);
  hipLaunchKernelGGL(yin_k,      dim3((N + 3) / 4), dim3(256), 0, stream,
                     rowptr, ecv, xin, yin);
  hipLaunchKernelGGL(gcn1,       dim3(N),  dim3(256), 0, stream, rowptr, ecv,
                     xcat8, yin, w1T, b1, state, xcat2, valu);
  hipLaunchKernelGGL(gcn2,       dim3(N),  dim3(256), 0, stream, rowptr, ecv,
                     xcat2, yin, w2T, b2, valu, state, out);
}

// Round 6
// 424.640 us; speedup vs baseline: 1.1975x; 1.1975x over previous
//
#include <hip/hip_runtime.h>
#include <hip/hip_fp16.h>
#include <cstdint>
#include <cstdio>

#define N_NODES 10000
#define BATCH   32
#define UNITS   64
#define F_DIM   66            // 2 + 64
#define XROW    2048          // fp8 state-part row bytes (64 f * 32 b)
#define KPAD    96            // MFMA K padded (3 x 32)
#define ASTR    104           // accH row stride in halves (96 + 8 pad)
#define GRP     8             // gather group size (2 groups in flight = 16 loads/wave)

typedef float v2f __attribute__((ext_vector_type(2)));
typedef float f32x4 __attribute__((ext_vector_type(4)));
typedef _Float16 half8 __attribute__((ext_vector_type(8)));

__device__ __forceinline__ float sigmoidf(float x) {
  return 1.0f / (1.0f + __expf(-x));
}

// ---------------- CSR build (+ weight prep folded in) ----------------
__global__ __launch_bounds__(256) void hist_k(const int* __restrict__ rows,
                                              int* __restrict__ counts, int E2,
                                              const float* __restrict__ w1,
                                              const float* __restrict__ w2,
                                              _Float16* __restrict__ w1T,
                                              _Float16* __restrict__ w2T) {
  int e = blockIdx.x * 256 + threadIdx.x;
  if (e < E2) atomicAdd(&counts[rows[e]], 1);
  if (e < 128 * KPAD) {
    int j = e / KPAD, f = e % KPAD;
    w1T[e] = (f < 66) ? (_Float16)w1[f * 128 + j] : (_Float16)0.0f;
  } else if (e < 128 * KPAD + 64 * KPAD) {
    int k = e - 128 * KPAD;
    int j = k / KPAD, f = k % KPAD;
    w2T[k] = (f < 66) ? (_Float16)w2[f * 64 + j] : (_Float16)0.0f;
  }
}

// Single block; counts staged through LDS with coalesced int4 loads.
__global__ __launch_bounds__(256) void scan_k(const int* __restrict__ counts,
                                              int* __restrict__ rowptr,
                                              int* __restrict__ wofs, int n) {
  __shared__ int lbuf[10240];
  __shared__ int sums[256];
  int t = threadIdx.x;
  for (int i = t; i < N_NODES / 4; i += 256)
    reinterpret_cast<int4*>(lbuf)[i] = reinterpret_cast<const int4*>(counts)[i];
  for (int i = N_NODES + t; i < 10240; i += 256) lbuf[i] = 0;
  __syncthreads();
  int base = t * 40;
  int v[40];
  int run = 0;
#pragma unroll
  for (int i = 0; i < 40; ++i) { v[i] = run; run += lbuf[base + i]; }
  sums[t] = run;
  __syncthreads();
  for (int off = 1; off < 256; off <<= 1) {
    int x = (t >= off) ? sums[t - off] : 0;
    __syncthreads();
    sums[t] += x;
    __syncthreads();
  }
  int tbase = (t == 0) ? 0 : sums[t - 1];
#pragma unroll
  for (int i = 0; i < 40; ++i) lbuf[base + i] = tbase + v[i];
  __syncthreads();
  for (int i = t; i < N_NODES / 4; i += 256) {
    int4 w = reinterpret_cast<int4*>(lbuf)[i];
    reinterpret_cast<int4*>(rowptr)[i] = w;
    reinterpret_cast<int4*>(wofs)[i] = w;
  }
  if (t == 255) rowptr[N_NODES] = sums[255];
}

// ---------------- fused scatter + phase-1 feature build ----------------
__device__ __forceinline__ void pack_row_fp8(const float* T, int n, int t,
                                             unsigned char* xcat8) {
  int k0 = t * 8;
  int f8 = k0 >> 5;
  int b0 = k0 & 31;
  const float* Ts = &T[(f8 + 2) * 33 + b0];
  int d0 = __builtin_amdgcn_cvt_pk_fp8_f32(Ts[0], Ts[1], 0, false);
  d0     = __builtin_amdgcn_cvt_pk_fp8_f32(Ts[2], Ts[3], d0, true);
  int d1 = __builtin_amdgcn_cvt_pk_fp8_f32(Ts[4], Ts[5], 0, false);
  d1     = __builtin_amdgcn_cvt_pk_fp8_f32(Ts[6], Ts[7], d1, true);
  *reinterpret_cast<uint2*>(xcat8 + (size_t)n * XROW + k0) = make_uint2(d0, d1);
}

// blocks [0, N_NODES): build xcat8 + xin for node n = blockIdx.x
// blocks [N_NODES, ...): scatter edges into ecv = {col*2048, bitcast(val)}
__global__ __launch_bounds__(256) void scat_build(const int* __restrict__ rows,
                                                  const int* __restrict__ cols,
                                                  const float* __restrict__ vals,
                                                  int* __restrict__ wofs,
                                                  int2* __restrict__ ecv, int E2,
                                                  const float* __restrict__ inputs,
                                                  const float* __restrict__ state,
                                                  unsigned char* __restrict__ xcat8,
                                                  __half2* __restrict__ xin) {
  int blk = blockIdx.x, t = threadIdx.x;
  if (blk >= N_NODES) {
    int e = (blk - N_NODES) * 256 + t;
    if (e < E2) {
      int r = rows[e];
      int p = atomicAdd(&wofs[r], 1);
      ecv[p] = make_int2(cols[e] << 11, __float_as_int(vals[e]));
    }
    return;
  }
  int n = blk;
  __shared__ float T[66 * 33];
  int f = t & 63, bq = t >> 6;
#pragma unroll
  for (int bb = 0; bb < 8; ++bb) {
    int b = bq + bb * 4;
    T[(f + 2) * 33 + b] = state[(size_t)b * 640000 + (size_t)n * 64 + f];
  }
  if (t < 64) {
    int b0 = t & 31, f0 = t >> 5;
    T[f0 * 33 + b0] = inputs[(size_t)b0 * 20000 + (size_t)n * 2 + f0];
  }
  __syncthreads();
  pack_row_fp8(T, n, t, xcat8);
  if (t < 32) {
    int f0 = t >> 4, b = (t & 15) * 2;
    xin[(size_t)n * 32 + t] = __floats2half2_rn(T[f0 * 33 + b], T[f0 * 33 + b + 1]);
  }
}

// ---------------- yin = M @ X_in ----------------
// Node-per-wave, 4 edges in parallel (16 lanes x 8B each), shfl reduce.
__global__ __launch_bounds__(256) void yin_k(const int* __restrict__ rowptr,
                                             const int2* __restrict__ ecv,
                                             const __half* __restrict__ xin,
                                             float* __restrict__ yin) {
  int n = (blockIdx.x * 256 + threadIdx.x) >> 6;     // node per wave
  if (n >= N_NODES) return;
  int lane  = threadIdx.x & 63;
  int eslot = lane >> 4;         // 0..3 : which edge of the 4-group
  int sub   = lane & 15;         // 0..15: which 8B chunk of the 128B row
  unsigned sb = (unsigned)sub * 8u;

  float acc0 = 0.0f, acc1 = 0.0f, acc2 = 0.0f, acc3 = 0.0f;
  int s = rowptr[n], e = rowptr[n + 1];
  const char* xb = reinterpret_cast<const char*>(xin);
  for (int ee = s + eslot; ee < e; ee += 4) {
    int2 cv = ecv[ee];
    float v = __int_as_float(cv.y);
    unsigned off = ((unsigned)cv.x >> 4) + sb;       // col*128 + sub*8
    uint2 raw = *reinterpret_cast<const uint2*>(xb + off);
    __half2 h0 = *reinterpret_cast<__half2*>(&raw.x);
    __half2 h1 = *reinterpret_cast<__half2*>(&raw.y);
    float2 x0 = __half22float2(h0);
    float2 x1 = __half22float2(h1);
    acc0 += v * x0.x; acc1 += v * x0.y;
    acc2 += v * x1.x; acc3 += v * x1.y;
  }
  // reduce across the 4 edge slots (lane ^16, ^32)
#pragma unroll
  for (int m = 16; m <= 32; m <<= 1) {
    acc0 += __shfl_xor(acc0, m);
    acc1 += __shfl_xor(acc1, m);
    acc2 += __shfl_xor(acc2, m);
    acc3 += __shfl_xor(acc3, m);
  }
  if (eslot == 0) {
    *reinterpret_cast<float4*>(yin + (size_t)n * 64 + sub * 4) =
        make_float4(acc0, acc1, acc2, acc3);
  }
}

// Consume one 8B chunk (8 fp8) into 4 packed-f32 accumulators (v_pk_fma_f32).
__device__ __forceinline__ void consume8f8(uint2 u, float v, v2f* acc) {
  v2f p0 = __builtin_amdgcn_cvt_pk_f32_fp8((int)u.x, false);
  v2f p1 = __builtin_amdgcn_cvt_pk_f32_fp8((int)u.x, true);
  v2f p2 = __builtin_amdgcn_cvt_pk_f32_fp8((int)u.y, false);
  v2f p3 = __builtin_amdgcn_cvt_pk_f32_fp8((int)u.y, true);
  v2f vv = {v, v};
  acc[0] += vv * p0;
  acc[1] += vv * p1;
  acc[2] += vv * p2;
  acc[3] += vv * p3;
}

// Load one group of GRP edges: edge meta via UNIFORM (scalar) loads, gathers
// issued as SADDR-form loads (uniform base + per-thread offset).
__device__ __forceinline__ void ld_grp(const int2* __restrict__ ep, int gsz,
                                       const unsigned char* __restrict__ xcat8,
                                       unsigned t8, uint2* r, float* v) {
#pragma unroll
  for (int q = 0; q < GRP; ++q) {
    int2 c = ep[q];                       // uniform -> s_load
    if (q >= gsz) { c.x = 0; c.y = 0; }   // masked tail: row 0, weight 0 (scalar ops)
    unsigned off = (unsigned)c.x + t8;    // 1 VALU add (SGPR + VGPR)
    r[q] = *reinterpret_cast<const uint2*>(xcat8 + off);
    v[q] = __int_as_float(c.y);           // stays scalar
  }
}

__device__ __forceinline__ void cons_grp(const uint2* r, const float* v, v2f* acc) {
#pragma unroll
  for (int q = 0; q < GRP; ++q) consume8f8(r[q], v[q], acc);
}

// Shared SpMM body: scalar edge stream, groups of GRP, double-buffered
// (2*GRP loads in flight / wave), no LDS edge staging, no barriers.
// Result staged to fp16 accH[b][k]: k=0,1 from yin, k=2..65 state part,
// k=66..95 zero-padded for MFMA.
__device__ __forceinline__ void spmm_body(int n, int t,
                                          const int* __restrict__ rowptr,
                                          const int2* __restrict__ ecv,
                                          const unsigned char* __restrict__ xcat8,
                                          const float* __restrict__ yin,
                                          _Float16* accH) {
  v2f acc[4];
#pragma unroll
  for (int i = 0; i < 4; ++i) acc[i] = (v2f){0.0f, 0.0f};

  unsigned t8 = (unsigned)t * 8u;
  int s = rowptr[n], e = rowptr[n + 1];
  int ne = e - s;
  int ng = (ne + GRP - 1) / GRP;
  const int2* ep = ecv + s;

  uint2 rA[GRP], rB[GRP];
  float vA[GRP], vB[GRP];
  ld_grp(ep, ne, xcat8, t8, rA, vA);
  int g = 1;
  for (; g + 1 < ng; g += 2) {
    ld_grp(ep + GRP * g, ne - GRP * g, xcat8, t8, rB, vB);
    cons_grp(rA, vA, acc);
    ld_grp(ep + GRP * (g + 1), ne - GRP * (g + 1), xcat8, t8, rA, vA);
    cons_grp(rB, vB, acc);
  }
  if (g < ng) {
    ld_grp(ep + GRP * g, ne - GRP * g, xcat8, t8, rB, vB);
    cons_grp(rA, vA, acc);
    cons_grp(rB, vB, acc);
  } else {
    cons_grp(rA, vA, acc);
  }

  // ---- stage into fp16 accH[b][k] ----
  {
    int f8 = t >> 2;
    int b0 = (t & 3) * 8;
    float a[8] = {acc[0].x, acc[0].y, acc[1].x, acc[1].y,
                  acc[2].x, acc[2].y, acc[3].x, acc[3].y};
    _Float16* dst = accH + (f8 + 2);
#pragma unroll
    for (int i = 0; i < 8; ++i) {
      dst[(b0 + i) * ASTR] = (_Float16)a[i];
    }
  }
  if (t < 64) {
    int f = t >> 5, b = t & 31;
    accH[b * ASTR + f] = (_Float16)yin[(size_t)n * 64 + t];
  }
  for (int id = t; id < 32 * 19; id += 256) {
    int b = id / 19, c = id % 19;
    *reinterpret_cast<unsigned int*>(
        reinterpret_cast<char*>(accH) + b * (ASTR * 2) + 132 + c * 4) = 0u;
  }
  __syncthreads();
}

// ---------------- phase 1: SpMM + MFMA GEMM + sigmoid ----------------
// LDS: single 8704B region; accH (6656B) aliased by vstage after fragment loads.
// n < 5000 : outputs are r-gates of nodes 2n,2n+1 -> emit fp8 x2 rows (r*state).
// n >= 5000: outputs are u-gates -> write fp16 valu rows (node index n-5000).
__global__ __launch_bounds__(256) void gcn1(const int* __restrict__ rowptr,
                                            const int2* __restrict__ ecv,
                                            const unsigned char* __restrict__ xcat8,
                                            const float* __restrict__ yin,
                                            const _Float16* __restrict__ w1T,
                                            const float* __restrict__ b1,
                                            const float* __restrict__ state,
                                            unsigned char* __restrict__ xcat2,
                                            __half* __restrict__ valu) {
  int n = blockIdx.x, t = threadIdx.x;
  __shared__ __align__(16) char smem[32 * 136 * 2];   // 8704 B shared region
  _Float16* accH = reinterpret_cast<_Float16*>(smem); // 6656 B during SpMM

  spmm_body(n, t, rowptr, ecv, xcat8, yin, accH);

  int wv = t >> 6, l = t & 63;
  int mt = wv & 1, ntb = (wv >> 1) * 4;
  int lr = l & 15, lg = l >> 4;
  const _Float16* aB = accH + (size_t)(mt * 16 + lr) * ASTR + lg * 8;
  half8 afr0 = *reinterpret_cast<const half8*>(aB);
  half8 afr1 = *reinterpret_cast<const half8*>(aB + 32);
  half8 afr2 = *reinterpret_cast<const half8*>(aB + 64);
  __syncthreads();                                    // accH dead; alias as vstage
  _Float16* vstage = reinterpret_cast<_Float16*>(smem);

#pragma unroll
  for (int tt = 0; tt < 4; ++tt) {
    int j = (ntb + tt) * 16 + lr;
    const _Float16* wB = w1T + (size_t)j * KPAD + lg * 8;
    f32x4 c = {0.0f, 0.0f, 0.0f, 0.0f};
    c = __builtin_amdgcn_mfma_f32_16x16x32_f16(afr0, *reinterpret_cast<const half8*>(wB), c, 0, 0, 0);
    c = __builtin_amdgcn_mfma_f32_16x16x32_f16(afr1, *reinterpret_cast<const half8*>(wB + 32), c, 0, 0, 0);
    c = __builtin_amdgcn_mfma_f32_16x16x32_f16(afr2, *reinterpret_cast<const half8*>(wB + 64), c, 0, 0, 0);
    float bj = b1[j];
#pragma unroll
    for (int i = 0; i < 4; ++i) {
      int b = mt * 16 + lg * 4 + i;
      vstage[b * 136 + j] = (_Float16)sigmoidf(c[i] + bj);
    }
  }
  __syncthreads();

  if (n < 5000) {
    // r-path: f = t&63 so state reads are 256B/wave coalesced.
    int nn_i = t >> 7;
    int f    = t & 63;
    int bg   = (t >> 6) & 1;
    int nn = n * 2 + nn_i;
    int jj = nn_i * 64 + f;
    const float* sp = state + (size_t)nn * 64 + f;
    const _Float16* vp = vstage + jj;
    int bbase = bg * 16;
    unsigned int d[4];
#pragma unroll
    for (int q = 0; q < 4; ++q) {
      int b0 = bbase + q * 4;
      float x0 = (float)vp[(b0 + 0) * 136] * sp[(size_t)(b0 + 0) * 640000];
      float x1 = (float)vp[(b0 + 1) * 136] * sp[(size_t)(b0 + 1) * 640000];
      float x2 = (float)vp[(b0 + 2) * 136] * sp[(size_t)(b0 + 2) * 640000];
      float x3 = (float)vp[(b0 + 3) * 136] * sp[(size_t)(b0 + 3) * 640000];
      int dd = __builtin_amdgcn_cvt_pk_fp8_f32(x0, x1, 0, false);
      dd     = __builtin_amdgcn_cvt_pk_fp8_f32(x2, x3, dd, true);
      d[q] = (unsigned)dd;
    }
    *reinterpret_cast<uint4*>(xcat2 + (size_t)nn * XROW + f * 32 + bbase) =
        make_uint4(d[0], d[1], d[2], d[3]);
  } else {
    // u-path: vectorized copy to valu (node index n-5000)
    int b = t >> 3, jg = t & 7;
    const uint4* src = reinterpret_cast<const uint4*>(vstage + b * 136 + jg * 16);
    uint4 q0 = src[0];
    uint4 q1 = src[1];
    __half* vb = valu + (size_t)(n - 5000) * 4096 + b * 128 + jg * 16;
    *reinterpret_cast<uint4*>(vb) = q0;
    *reinterpret_cast<uint4*>(vb + 8) = q1;
  }
}

// ---------------- phase 2: SpMM + MFMA GEMM(96->64) + relu + gate -> out ----------------
__global__ __launch_bounds__(256) void gcn2(const int* __restrict__ rowptr,
                                            const int2* __restrict__ ecv,
                                            const unsigned char* __restrict__ xcat2,
                                            const float* __restrict__ yin,
                                            const _Float16* __restrict__ w2T,
                                            const float* __restrict__ b2,
                                            const __half* __restrict__ valu,
                                            const float* __restrict__ state,
                                            float* __restrict__ out) {
  int n = blockIdx.x, t = threadIdx.x;
  __shared__ __align__(16) char smem[32 * 68 * 4];    // 8704 B shared region
  _Float16* accH = reinterpret_cast<_Float16*>(smem); // 6656 B during SpMM

  spmm_body(n, t, rowptr, ecv, xcat2, yin, accH);

  int wv = t >> 6, l = t & 63;
  int mt = wv & 1, ntb = (wv >> 1) * 2;
  int lr = l & 15, lg = l >> 4;
  const _Float16* aB = accH + (size_t)(mt * 16 + lr) * ASTR + lg * 8;
  half8 afr0 = *reinterpret_cast<const half8*>(aB);
  half8 afr1 = *reinterpret_cast<const half8*>(aB + 32);
  half8 afr2 = *reinterpret_cast<const half8*>(aB + 64);
  __syncthreads();                                    // accH dead; alias as ostage
  float* ostage = reinterpret_cast<float*>(smem);     // [32][68]

#pragma unroll
  for (int tt = 0; tt < 2; ++tt) {
    int j = (ntb + tt) * 16 + lr;
    const _Float16* wB = w2T + (size_t)j * KPAD + lg * 8;
    f32x4 c = {0.0f, 0.0f, 0.0f, 0.0f};
    c = __builtin_amdgcn_mfma_f32_16x16x32_f16(afr0, *reinterpret_cast<const half8*>(wB), c, 0, 0, 0);
    c = __builtin_amdgcn_mfma_f32_16x16x32_f16(afr1, *reinterpret_cast<const half8*>(wB + 32), c, 0, 0, 0);
    c = __builtin_amdgcn_mfma_f32_16x16x32_f16(afr2, *reinterpret_cast<const half8*>(wB + 64), c, 0, 0, 0);
    float bj = b2[j];
#pragma unroll
    for (int i = 0; i < 4; ++i) {
      int b = mt * 16 + lg * 4 + i;
      ostage[b * 68 + j] = fmaxf(c[i] + bj, 0.0f);
    }
  }
  __syncthreads();

  int bg = t >> 4, jg = t & 15;
  int n2 = n >> 1, no = n & 1;
  const __half* up = valu + (size_t)n2 * 4096 + (size_t)no * 64 + jg * 4;
#pragma unroll
  for (int i = 0; i < 2; ++i) {
    int b = bg * 2 + i;
    size_t idx = (size_t)b * 640000 + (size_t)n * 64 + jg * 4;
    float4 sv = *reinterpret_cast<const float4*>(state + idx);
    float4 cc = *reinterpret_cast<const float4*>(ostage + b * 68 + jg * 4);
    union { uint2 u; __half2 h[2]; } pk;
    pk.u = *reinterpret_cast<const uint2*>(up + (size_t)b * 128);
    float2 u01 = __half22float2(pk.h[0]);
    float2 u23 = __half22float2(pk.h[1]);
    float4 h;
    h.x = u01.x * sv.x + (1.0f - u01.x) * cc.x;
    h.y = u01.y * sv.y + (1.0f - u01.y) * cc.y;
    h.z = u23.x * sv.z + (1.0f - u23.x) * cc.z;
    h.w = u23.y * sv.w + (1.0f - u23.y) * cc.w;
    *reinterpret_cast<float4*>(out + idx) = h;
  }
}

// ---------------- host ----------------
static inline size_t alignup(size_t x) { return (x + 255) & ~(size_t)255; }

extern "C" void kernel_launch(void* const* d_in, const int* in_sizes, int n_in,
                              void* d_out, int out_size, void* d_ws, size_t ws_size,
                              hipStream_t stream) {
  const float* inputs = (const float*)d_in[0];
  const float* state  = (const float*)d_in[1];
  const int*   m_rows = (const int*)d_in[2];
  const int*   m_cols = (const int*)d_in[3];
  const float* m_vals = (const float*)d_in[4];
  const float* w1     = (const float*)d_in[5];
  const float* b1     = (const float*)d_in[6];
  const float* w2     = (const float*)d_in[7];
  const float* b2     = (const float*)d_in[8];
  float* out = (float*)d_out;

  const int N  = N_NODES;
  const int E2 = in_sizes[2];

  char* ws = (char*)d_ws;
  size_t off = 0;
  int* counts = (int*)(ws + off); off = alignup(off + (size_t)N * 4);
  int* rowptr = (int*)(ws + off); off = alignup(off + (size_t)(N + 1) * 4);
  int* wofs   = (int*)(ws + off); off = alignup(off + (size_t)N * 4);
  int2* ecv   = (int2*)(ws + off); off = alignup(off + (size_t)E2 * 8 + 256); // +slack for group over-read
  unsigned char* xcat8 = (unsigned char*)(ws + off); off = alignup(off + (size_t)N * XROW);
  unsigned char* xcat2 = (unsigned char*)(ws + off); off = alignup(off + (size_t)N * XROW);
  __half* valu = (__half*)(ws + off); off = alignup(off + (size_t)5000 * 4096 * 2);
  float* yin  = (float*)(ws + off); off = alignup(off + (size_t)N * 64 * 4);
  __half* xin = (__half*)(ws + off); off = alignup(off + (size_t)N * 64 * 2);
  _Float16* w1T = (_Float16*)(ws + off); off = alignup(off + (size_t)128 * KPAD * 2);
  _Float16* w2T = (_Float16*)(ws + off); off = alignup(off + (size_t)64 * KPAD * 2);
  if (off > ws_size) { return; }

  hipMemsetAsync(counts, 0, (size_t)N * 4, stream);

  int eb = (E2 + 255) / 256;
  hipLaunchKernelGGL(hist_k,     dim3(eb), dim3(256), 0, stream, m_rows, counts, E2,
                     w1, w2, w1T, w2T);
  hipLaunchKernelGGL(scan_k,     dim3(1),  dim3(256), 0, stream, counts, rowptr, wofs, N);
  hipLaunchKernelGGL(scat_build, dim3(N + eb), dim3(256), 0, stream,
                     m_rows, m_cols, m_vals, wofs, ecv, E2,
                     inputs, state, xcat8, (__half2*)xin);
  hipLaunchKernelGGL(yin_k,      dim3((N + 3) / 4), dim3(256), 0, stream,
                     rowptr, ecv, xin, yin);
  hipLaunchKernelGGL(gcn1,       dim3(N),  dim3(256), 0, stream, rowptr, ecv,
                     xcat8, yin, w1T, b1, state, xcat2, valu);
  hipLaunchKernelGGL(gcn2,       dim3(N),  dim3(256), 0, stream, rowptr, ecv,
                     xcat2, yin, w2T, b2, valu, state, out);
}

// Round 7
// 368.392 us; speedup vs baseline: 1.3804x; 1.1527x over previous
//
#include <hip/hip_runtime.h>
#include <hip/hip_fp16.h>
#include <cstdint>
#include <cstdio>

#define N_NODES 10000
#define BATCH   32
#define UNITS   64
#define KPAD    96            // MFMA K padded (3 x 32)
#define ASTR    104           // accH row stride in halves (96 + 8 pad)
#define GRP     8             // gather group size (2 groups in flight)
#define NGRP    2500          // node groups (4 nodes each)
#define NBLK    20000         // NGRP * 8 slices

typedef float v2f __attribute__((ext_vector_type(2)));
typedef float f32x4 __attribute__((ext_vector_type(4)));
typedef _Float16 half8 __attribute__((ext_vector_type(8)));

__device__ __forceinline__ float sigmoidf(float x) {
  return 1.0f / (1.0f + __expf(-x));
}

// ---------------- CSR build (+ weight prep folded in) ----------------
__global__ __launch_bounds__(256) void hist_k(const int* __restrict__ rows,
                                              int* __restrict__ counts, int E2,
                                              const float* __restrict__ w1,
                                              const float* __restrict__ w2,
                                              _Float16* __restrict__ w1T,
                                              _Float16* __restrict__ w2T) {
  int e = blockIdx.x * 256 + threadIdx.x;
  if (e < E2) atomicAdd(&counts[rows[e]], 1);
  if (e < 128 * KPAD) {
    int j = e / KPAD, f = e % KPAD;
    w1T[e] = (f < 66) ? (_Float16)w1[f * 128 + j] : (_Float16)0.0f;
  } else if (e < 128 * KPAD + 64 * KPAD) {
    int k = e - 128 * KPAD;
    int j = k / KPAD, f = k % KPAD;
    w2T[k] = (f < 66) ? (_Float16)w2[f * 64 + j] : (_Float16)0.0f;
  }
}

// Single block; counts staged through LDS with coalesced int4 loads.
__global__ __launch_bounds__(256) void scan_k(const int* __restrict__ counts,
                                              int* __restrict__ rowptr,
                                              int* __restrict__ wofs, int n) {
  __shared__ int lbuf[10240];
  __shared__ int sums[256];
  int t = threadIdx.x;
  for (int i = t; i < N_NODES / 4; i += 256)
    reinterpret_cast<int4*>(lbuf)[i] = reinterpret_cast<const int4*>(counts)[i];
  for (int i = N_NODES + t; i < 10240; i += 256) lbuf[i] = 0;
  __syncthreads();
  int base = t * 40;
  int v[40];
  int run = 0;
#pragma unroll
  for (int i = 0; i < 40; ++i) { v[i] = run; run += lbuf[base + i]; }
  sums[t] = run;
  __syncthreads();
  for (int off = 1; off < 256; off <<= 1) {
    int x = (t >= off) ? sums[t - off] : 0;
    __syncthreads();
    sums[t] += x;
    __syncthreads();
  }
  int tbase = (t == 0) ? 0 : sums[t - 1];
#pragma unroll
  for (int i = 0; i < 40; ++i) lbuf[base + i] = tbase + v[i];
  __syncthreads();
  for (int i = t; i < N_NODES / 4; i += 256) {
    int4 w = reinterpret_cast<int4*>(lbuf)[i];
    reinterpret_cast<int4*>(rowptr)[i] = w;
    reinterpret_cast<int4*>(wofs)[i] = w;
  }
  if (t == 255) rowptr[N_NODES] = sums[255];
}

// ---------------- fused scatter + sliced phase-1 feature build ----------------
// Sliced table layout: xcat[s][n][f*4 + bi], s = b>>2, bi = b&3. Row = 256 B.
// blocks [0, NBLK): blk = g*8... actually blk&7 = slice, blk>>3 = node group.
// blocks [NBLK, ...): scatter edges into ecv = {col*256, bitcast(val)}.
__global__ __launch_bounds__(256) void scat_build(const int* __restrict__ rows,
                                                  const int* __restrict__ cols,
                                                  const float* __restrict__ vals,
                                                  int* __restrict__ wofs,
                                                  int2* __restrict__ ecv, int E2,
                                                  const float* __restrict__ inputs,
                                                  const float* __restrict__ state,
                                                  unsigned char* __restrict__ xcat,
                                                  __half* __restrict__ xin) {
  int blk = blockIdx.x, t = threadIdx.x;
  if (blk >= NBLK) {
    int e = (blk - NBLK) * 256 + t;
    if (e < E2) {
      int r = rows[e];
      int p = atomicAdd(&wofs[r], 1);
      ecv[p] = make_int2(cols[e] << 8, __float_as_int(vals[e]));
    }
    return;
  }
  int g = blk >> 3, s = blk & 7;
  int wv = t >> 6, lane = t & 63;
  int n = g * 4 + wv;
  float x[4];
#pragma unroll
  for (int bi = 0; bi < 4; ++bi)
    x[bi] = state[(size_t)(s * 4 + bi) * 640000 + (size_t)n * 64 + lane];
  int d = __builtin_amdgcn_cvt_pk_fp8_f32(x[0], x[1], 0, false);
  d     = __builtin_amdgcn_cvt_pk_fp8_f32(x[2], x[3], d, true);
  *reinterpret_cast<unsigned*>(xcat + (((size_t)(s * N_NODES + n)) << 8) + lane * 4) =
      (unsigned)d;
  if (lane < 8) {
    int bi = lane >> 1, f = lane & 1;
    float v = inputs[(size_t)(s * 4 + bi) * 20000 + (size_t)n * 2 + f];
    xin[(size_t)n * 64 + f * 32 + s * 4 + bi] = (__half)v;
  }
}

// ---------------- yin = M @ X_in ----------------
// Node-per-wave, 4 edges in parallel (16 lanes x 8B each), shfl reduce.
__global__ __launch_bounds__(256) void yin_k(const int* __restrict__ rowptr,
                                             const int2* __restrict__ ecv,
                                             const __half* __restrict__ xin,
                                             float* __restrict__ yin) {
  int n = (blockIdx.x * 256 + threadIdx.x) >> 6;     // node per wave
  if (n >= N_NODES) return;
  int lane  = threadIdx.x & 63;
  int eslot = lane >> 4;
  int sub   = lane & 15;
  unsigned sb = (unsigned)sub * 8u;

  float acc0 = 0.0f, acc1 = 0.0f, acc2 = 0.0f, acc3 = 0.0f;
  int s = rowptr[n], e = rowptr[n + 1];
  const char* xb = reinterpret_cast<const char*>(xin);
  for (int ee = s + eslot; ee < e; ee += 4) {
    int2 cv = ecv[ee];
    float v = __int_as_float(cv.y);
    unsigned off = ((unsigned)cv.x >> 1) + sb;       // col*128 + sub*8
    uint2 raw = *reinterpret_cast<const uint2*>(xb + off);
    __half2 h0 = *reinterpret_cast<__half2*>(&raw.x);
    __half2 h1 = *reinterpret_cast<__half2*>(&raw.y);
    float2 x0 = __half22float2(h0);
    float2 x1 = __half22float2(h1);
    acc0 += v * x0.x; acc1 += v * x0.y;
    acc2 += v * x1.x; acc3 += v * x1.y;
  }
#pragma unroll
  for (int m = 16; m <= 32; m <<= 1) {
    acc0 += __shfl_xor(acc0, m);
    acc1 += __shfl_xor(acc1, m);
    acc2 += __shfl_xor(acc2, m);
    acc3 += __shfl_xor(acc3, m);
  }
  if (eslot == 0) {
    *reinterpret_cast<float4*>(yin + (size_t)n * 64 + sub * 4) =
        make_float4(acc0, acc1, acc2, acc3);
  }
}

// ---------------- sliced SpMM (per-wave node, per-block slice) ----------------
__device__ __forceinline__ void ld_grp4(const int2* __restrict__ ep, int gsz,
                                        const char* __restrict__ xb,
                                        unsigned* r, float* v) {
#pragma unroll
  for (int q = 0; q < GRP; ++q) {
    int2 c = ep[q];                       // uniform -> s_load
    if (q >= gsz) { c.x = 0; c.y = 0; }   // masked tail
    r[q] = *reinterpret_cast<const unsigned*>(xb + (unsigned)c.x);
    v[q] = __int_as_float(c.y);
  }
}

__device__ __forceinline__ void cons_grp4(const unsigned* r, const float* v, v2f* acc) {
#pragma unroll
  for (int q = 0; q < GRP; ++q) {
    v2f p0 = __builtin_amdgcn_cvt_pk_f32_fp8((int)r[q], false);
    v2f p1 = __builtin_amdgcn_cvt_pk_f32_fp8((int)r[q], true);
    v2f vv = {v[q], v[q]};
    acc[0] += vv * p0;
    acc[1] += vv * p1;
  }
}

// Each wave: one node, this block's slice. lane = feature f (0..63), 4 fp8 (bi 0..3)
// per edge per lane. Stages accH[16][ASTR]: rows m = node_i*4+bi, k=2+f state part,
// k=0,1 from yin, k=66..95 zero.
__device__ __forceinline__ void spmm_slice(int g, int s, int t,
                                           const int* __restrict__ rowptr,
                                           const int2* __restrict__ ecv,
                                           const unsigned char* __restrict__ xcat,
                                           const float* __restrict__ yin,
                                           _Float16* accH) {
  int wv = t >> 6, lane = t & 63;
  int n = g * 4 + wv;
  const char* xb = reinterpret_cast<const char*>(xcat) +
                   (((size_t)(s * N_NODES)) << 8) + (unsigned)lane * 4;
  int se = __builtin_amdgcn_readfirstlane(rowptr[n]);
  int ee = __builtin_amdgcn_readfirstlane(rowptr[n + 1]);
  int ne = ee - se;
  int ng = (ne + GRP - 1) / GRP;
  const int2* ep = ecv + se;

  v2f acc[2];
  acc[0] = (v2f){0.0f, 0.0f};
  acc[1] = (v2f){0.0f, 0.0f};

  unsigned rA[GRP], rB[GRP];
  float vA[GRP], vB[GRP];
  ld_grp4(ep, ne, xb, rA, vA);
  int gg = 1;
  for (; gg + 1 < ng; gg += 2) {
    ld_grp4(ep + GRP * gg, ne - GRP * gg, xb, rB, vB);
    cons_grp4(rA, vA, acc);
    ld_grp4(ep + GRP * (gg + 1), ne - GRP * (gg + 1), xb, rA, vA);
    cons_grp4(rB, vB, acc);
  }
  if (gg < ng) {
    ld_grp4(ep + GRP * gg, ne - GRP * gg, xb, rB, vB);
    cons_grp4(rA, vA, acc);
    cons_grp4(rB, vB, acc);
  } else {
    cons_grp4(rA, vA, acc);
  }

  // stage: rows m = wv*4 + bi, col k = 2 + lane
  {
    _Float16* dst = accH + (size_t)(wv * 4) * ASTR + 2 + lane;
    dst[0 * ASTR] = (_Float16)acc[0].x;
    dst[1 * ASTR] = (_Float16)acc[0].y;
    dst[2 * ASTR] = (_Float16)acc[1].x;
    dst[3 * ASTR] = (_Float16)acc[1].y;
  }
  if (t < 240) {          // zero pad k = 66..95: 15 dwords x 16 rows
    int m = t / 15, d2 = t % 15;
    *reinterpret_cast<unsigned*>(
        reinterpret_cast<char*>(accH) + m * (ASTR * 2) + 132 + d2 * 4) = 0u;
  } else {                // yin: k = 0,1 for row m = t-240
    int m = t - 240;
    int bi = m & 3, ni = m >> 2;
    int nn = g * 4 + ni;
    accH[m * ASTR + 0] = (_Float16)yin[(size_t)nn * 64 + s * 4 + bi];
    accH[m * ASTR + 1] = (_Float16)yin[(size_t)nn * 64 + 32 + s * 4 + bi];
  }
  __syncthreads();
}

// ---------------- phase 1: sliced SpMM + MFMA(16x96 -> 16x128) + sigmoid ----------------
// g < 1250 : r-gates of nodes 2n,2n+1 -> emit sliced fp8 xcat2 rows (r*state).
// g >= 1250: u-gates -> valu[s][n-5000][bi][128] fp16.
__global__ __launch_bounds__(256) void gcn1(const int* __restrict__ rowptr,
                                            const int2* __restrict__ ecv,
                                            const unsigned char* __restrict__ xcat,
                                            const float* __restrict__ yin,
                                            const _Float16* __restrict__ w1T,
                                            const float* __restrict__ b1,
                                            const float* __restrict__ state,
                                            unsigned char* __restrict__ xcat2,
                                            __half* __restrict__ valu) {
  int blk = blockIdx.x, t = threadIdx.x;
  int g = blk >> 3, s = blk & 7;
  __shared__ __align__(16) char smem[16 * 136 * 2];   // 4352 B
  _Float16* accH = reinterpret_cast<_Float16*>(smem); // 3328 B during SpMM

  spmm_slice(g, s, t, rowptr, ecv, xcat, yin, accH);

  int wv = t >> 6, lane = t & 63;
  int lr = lane & 15, lg = lane >> 4;
  const _Float16* aB = accH + (size_t)lr * ASTR + lg * 8;
  half8 a0 = *reinterpret_cast<const half8*>(aB);
  half8 a1 = *reinterpret_cast<const half8*>(aB + 32);
  half8 a2 = *reinterpret_cast<const half8*>(aB + 64);
  __syncthreads();                                    // accH dead; alias vstage
  _Float16* vstage = reinterpret_cast<_Float16*>(smem); // [16][136]

#pragma unroll
  for (int tt = 0; tt < 2; ++tt) {
    int j = (wv * 2 + tt) * 16 + lr;
    const _Float16* wB = w1T + (size_t)j * KPAD + lg * 8;
    f32x4 c = {0.0f, 0.0f, 0.0f, 0.0f};
    c = __builtin_amdgcn_mfma_f32_16x16x32_f16(a0, *reinterpret_cast<const half8*>(wB), c, 0, 0, 0);
    c = __builtin_amdgcn_mfma_f32_16x16x32_f16(a1, *reinterpret_cast<const half8*>(wB + 32), c, 0, 0, 0);
    c = __builtin_amdgcn_mfma_f32_16x16x32_f16(a2, *reinterpret_cast<const half8*>(wB + 64), c, 0, 0, 0);
    float bj = b1[j];
#pragma unroll
    for (int i = 0; i < 4; ++i) {
      vstage[(lg * 4 + i) * 136 + j] = (_Float16)sigmoidf(c[i] + bj);
    }
  }
  __syncthreads();

  if (g < 1250) {
    // r-path: thread t -> node_i = t>>6, rem = t&63 -> j = rem*2, rem*2+1
    int node_i = t >> 6, rem = t & 63;
    int nglob = g * 4 + node_i;
    int nn = 2 * nglob + (rem >> 5);
    int f0 = (rem * 2) & 63;
    int mrow = node_i * 4;
    int j0 = rem * 2;
    float2 st[4];
#pragma unroll
    for (int bi = 0; bi < 4; ++bi)
      st[bi] = *reinterpret_cast<const float2*>(
          state + (size_t)(s * 4 + bi) * 640000 + (size_t)nn * 64 + f0);
    unsigned dq[2];
#pragma unroll
    for (int q = 0; q < 2; ++q) {
      float y0 = (float)vstage[(mrow + 0) * 136 + j0 + q] * (q ? st[0].y : st[0].x);
      float y1 = (float)vstage[(mrow + 1) * 136 + j0 + q] * (q ? st[1].y : st[1].x);
      float y2 = (float)vstage[(mrow + 2) * 136 + j0 + q] * (q ? st[2].y : st[2].x);
      float y3 = (float)vstage[(mrow + 3) * 136 + j0 + q] * (q ? st[3].y : st[3].x);
      int dd = __builtin_amdgcn_cvt_pk_fp8_f32(y0, y1, 0, false);
      dd     = __builtin_amdgcn_cvt_pk_fp8_f32(y2, y3, dd, true);
      dq[q] = (unsigned)dd;
    }
    *reinterpret_cast<uint2*>(xcat2 + (((size_t)(s * N_NODES + nn)) << 8) + f0 * 4) =
        make_uint2(dq[0], dq[1]);
  } else {
    // u-path: copy vstage row segments to valu[s][nm][bi][128]
    int node_i = t >> 6;
    int bi = (t >> 4) & 3, jq = (t & 15) * 8;
    int nm = g * 4 + node_i - 5000;
    uint4 q0 = *reinterpret_cast<const uint4*>(vstage + (node_i * 4 + bi) * 136 + jq);
    *reinterpret_cast<uint4*>(
        valu + ((size_t)(s * 5000 + nm) * 4 + bi) * 128 + jq) = q0;
  }
}

// ---------------- phase 2: sliced SpMM + MFMA(16x96 -> 16x64) + relu + gate ----------------
__global__ __launch_bounds__(256) void gcn2(const int* __restrict__ rowptr,
                                            const int2* __restrict__ ecv,
                                            const unsigned char* __restrict__ xcat2,
                                            const float* __restrict__ yin,
                                            const _Float16* __restrict__ w2T,
                                            const float* __restrict__ b2,
                                            const __half* __restrict__ valu,
                                            const float* __restrict__ state,
                                            float* __restrict__ out) {
  int blk = blockIdx.x, t = threadIdx.x;
  int g = blk >> 3, s = blk & 7;
  __shared__ __align__(16) char smem[16 * 68 * 4];    // 4352 B
  _Float16* accH = reinterpret_cast<_Float16*>(smem);

  spmm_slice(g, s, t, rowptr, ecv, xcat2, yin, accH);

  int wv = t >> 6, lane = t & 63;
  int lr = lane & 15, lg = lane >> 4;
  const _Float16* aB = accH + (size_t)lr * ASTR + lg * 8;
  half8 a0 = *reinterpret_cast<const half8*>(aB);
  half8 a1 = *reinterpret_cast<const half8*>(aB + 32);
  half8 a2 = *reinterpret_cast<const half8*>(aB + 64);
  __syncthreads();                                    // accH dead; alias ostage
  float* ostage = reinterpret_cast<float*>(smem);     // [16][68]

  {
    int j = wv * 16 + lr;
    const _Float16* wB = w2T + (size_t)j * KPAD + lg * 8;
    f32x4 c = {0.0f, 0.0f, 0.0f, 0.0f};
    c = __builtin_amdgcn_mfma_f32_16x16x32_f16(a0, *reinterpret_cast<const half8*>(wB), c, 0, 0, 0);
    c = __builtin_amdgcn_mfma_f32_16x16x32_f16(a1, *reinterpret_cast<const half8*>(wB + 32), c, 0, 0, 0);
    c = __builtin_amdgcn_mfma_f32_16x16x32_f16(a2, *reinterpret_cast<const half8*>(wB + 64), c, 0, 0, 0);
    float bj = b2[j];
#pragma unroll
    for (int i = 0; i < 4; ++i) {
      ostage[(lg * 4 + i) * 68 + j] = fmaxf(c[i] + bj, 0.0f);
    }
  }
  __syncthreads();

  // gate: new_h = u*state + (1-u)*c
  int node_i = t >> 6;
  int bi = (t >> 4) & 3, f0 = (t & 15) * 4;
  int n = g * 4 + node_i;
  size_t idx = (size_t)(s * 4 + bi) * 640000 + (size_t)n * 64 + f0;
  float4 sv = *reinterpret_cast<const float4*>(state + idx);
  float4 cc = *reinterpret_cast<const float4*>(ostage + (node_i * 4 + bi) * 68 + f0);
  const __half* up = valu + ((size_t)(s * 5000 + (n >> 1)) * 4 + bi) * 128 +
                     (n & 1) * 64 + f0;
  union { uint2 u; __half2 h[2]; } pk;
  pk.u = *reinterpret_cast<const uint2*>(up);
  float2 u01 = __half22float2(pk.h[0]);
  float2 u23 = __half22float2(pk.h[1]);
  float4 h;
  h.x = u01.x * sv.x + (1.0f - u01.x) * cc.x;
  h.y = u01.y * sv.y + (1.0f - u01.y) * cc.y;
  h.z = u23.x * sv.z + (1.0f - u23.x) * cc.z;
  h.w = u23.y * sv.w + (1.0f - u23.y) * cc.w;
  *reinterpret_cast<float4*>(out + idx) = h;
}

// ---------------- host ----------------
static inline size_t alignup(size_t x) { return (x + 255) & ~(size_t)255; }

extern "C" void kernel_launch(void* const* d_in, const int* in_sizes, int n_in,
                              void* d_out, int out_size, void* d_ws, size_t ws_size,
                              hipStream_t stream) {
  const float* inputs = (const float*)d_in[0];
  const float* state  = (const float*)d_in[1];
  const int*   m_rows = (const int*)d_in[2];
  const int*   m_cols = (const int*)d_in[3];
  const float* m_vals = (const float*)d_in[4];
  const float* w1     = (const float*)d_in[5];
  const float* b1     = (const float*)d_in[6];
  const float* w2     = (const float*)d_in[7];
  const float* b2     = (const float*)d_in[8];
  float* out = (float*)d_out;

  const int N  = N_NODES;
  const int E2 = in_sizes[2];

  char* ws = (char*)d_ws;
  size_t off = 0;
  int* counts = (int*)(ws + off); off = alignup(off + (size_t)N * 4);
  int* rowptr = (int*)(ws + off); off = alignup(off + (size_t)(N + 1) * 4);
  int* wofs   = (int*)(ws + off); off = alignup(off + (size_t)N * 4);
  int2* ecv   = (int2*)(ws + off); off = alignup(off + (size_t)E2 * 8 + 256); // +group over-read slack
  unsigned char* xcat  = (unsigned char*)(ws + off); off = alignup(off + (size_t)8 * N * 256);
  unsigned char* xcat2 = (unsigned char*)(ws + off); off = alignup(off + (size_t)8 * N * 256);
  __half* valu = (__half*)(ws + off); off = alignup(off + (size_t)5000 * 4096 * 2);
  float* yin  = (float*)(ws + off); off = alignup(off + (size_t)N * 64 * 4);
  __half* xin = (__half*)(ws + off); off = alignup(off + (size_t)N * 64 * 2);
  _Float16* w1T = (_Float16*)(ws + off); off = alignup(off + (size_t)128 * KPAD * 2);
  _Float16* w2T = (_Float16*)(ws + off); off = alignup(off + (size_t)64 * KPAD * 2);
  if (off > ws_size) { return; }

  hipMemsetAsync(counts, 0, (size_t)N * 4, stream);

  int eb = (E2 + 255) / 256;
  hipLaunchKernelGGL(hist_k,     dim3(eb), dim3(256), 0, stream, m_rows, counts, E2,
                     w1, w2, w1T, w2T);
  hipLaunchKernelGGL(scan_k,     dim3(1),  dim3(256), 0, stream, counts, rowptr, wofs, N);
  hipLaunchKernelGGL(scat_build, dim3(NBLK + eb), dim3(256), 0, stream,
                     m_rows, m_cols, m_vals, wofs, ecv, E2,
                     inputs, state, xcat, xin);
  hipLaunchKernelGGL(yin_k,      dim3((N + 3) / 4), dim3(256), 0, stream,
                     rowptr, ecv, xin, yin);
  hipLaunchKernelGGL(gcn1,       dim3(NBLK), dim3(256), 0, stream, rowptr, ecv,
                     xcat, yin, w1T, b1, state, xcat2, valu);
  hipLaunchKernelGGL(gcn2,       dim3(NBLK), dim3(256), 0, stream, rowptr, ecv,
                     xcat2, yin, w2T, b2, valu, state, out);
}